// Round 5
// baseline (252.196 us; speedup 1.0000x reference)
//
#include <hip/hip_runtime.h>
#include <math.h>

// Problem constants
#define B_    32
#define L_    4096
#define CIN_  128
#define H_    256
#define T_    4094          // L - K + 1
#define KTOT_ 384           // CIN * K

#define MT_   128           // timesteps per block (M tile)
#define NTB_  32            // t-blocks (32 * 128 = 4096)
#define NG_   192           // channels per block (z,f,o x 64 h)
#define NKT_  12            // K-steps of 32
#define GP_   196           // gate LDS pitch in f32

typedef float f32x4 __attribute__((ext_vector_type(4)));
typedef short s16x8 __attribute__((ext_vector_type(8)));

static __device__ __forceinline__ unsigned short f2bf(float f) {
  unsigned u = __builtin_bit_cast(unsigned, f);
  u = (u + 0x7FFFu + ((u >> 16) & 1u)) >> 16;
  return (unsigned short)u;
}

// ---------------------------------------------------------------------------
// Kernel 0: pack W (oc, i, k) fp32 -> bf16 [g][kt][kgrp][c192][e8]
// B-fragment for (lane lr,lg / wave wn / nj / step kt) is 16 contiguous bytes.
// ---------------------------------------------------------------------------
__global__ __launch_bounds__(256) void packW_bf16(const float* __restrict__ W,
                                                  unsigned short* __restrict__ Wb) {
  const int idx = blockIdx.x * 256 + threadIdx.x;     // 294912 = 1152*256
  const int e = idx & 7;
  int t = idx >> 3;
  const int c = t % NG_;
  t /= NG_;
  const int kgrp = t & 3;
  t >>= 2;
  const int kt = t % NKT_;
  const int g = t / NKT_;
  const int kk = kt * 32 + kgrp * 8 + e;
  const int i = kk & 127, k = kk >> 7;
  const int gate = c >> 6, hl = c & 63;
  const int oc = gate * 256 + g * 64 + hl;
  Wb[idx] = f2bf(W[(size_t)oc * KTOT_ + i * 3 + k]);
}

// ---------------------------------------------------------------------------
// Kernel 1: fused bf16-MFMA conv + activations + fo-pool scan + block compose.
// grid (1024 = tblk*32+b, 4 h-groups), block 512 (8 waves = 2M x 4N).
// Barrier-free K-loop (A in LDS read-only, B global->VGPR from L1/L2).
// Each block emits ONE affine (P,S) covering its 128 timesteps.
// ---------------------------------------------------------------------------
__global__ __launch_bounds__(512, 6) void conv_scan_mfma(
    const float* __restrict__ x, const unsigned short* __restrict__ Wb,
    const float* __restrict__ bias, float* __restrict__ Pc,
    float* __restrict__ Sc) {
  // xs: 130 rows x 128 bf16 (256B pitch, XOR-swizzled) = 33280 B
  // gs (scan, overlays xs): 32 x GP_ f32                = 25088 B
  // pbuf (chunk results, after gs): 32 x 64 x 2 f32     = 16384 B
  __shared__ __align__(16) char smem[25088 + 16384];
  char* xs = smem;
  float* gs = (float*)smem;
  float* pbuf = (float*)(smem + 25088);

  const int tid = threadIdx.x;
  const int w = tid >> 6;              // wave 0..7
  const int wm = w >> 2;               // M half: rows [64*wm, 64*wm+64)
  const int wn = w & 3;                // N quarter: cols [48*wn, 48*wn+48)
  const int l = tid & 63;
  const int lr = l & 15;
  const int lg = l >> 4;
  const int tb = blockIdx.x;
  const int g = blockIdx.y;            // h-group 0..3
  const int bb = tb & 31;
  const int tblk = tb >> 5;
  const int t0 = tblk * MT_;

  // ---- stage x slice (130 rows) fp32 -> bf16 into swizzled xs ----
  for (int v = tid; v < 130 * 32; v += 512) {
    const int row = v >> 5;
    const int colb = (v & 31) * 8;               // byte offset of 4 bf16
    int r = t0 + row;
    if (r > L_ - 1) r = L_ - 1;                  // clamp; feeds only t>=T_, skipped
    const float4 xv = *(const float4*)&x[((size_t)bb * L_ + r) * CIN_ + (v & 31) * 4];
    unsigned p0, p1;
    asm("v_cvt_pk_bf16_f32 %0, %1, %2" : "=v"(p0) : "v"(xv.x), "v"(xv.y));
    asm("v_cvt_pk_bf16_f32 %0, %1, %2" : "=v"(p1) : "v"(xv.z), "v"(xv.w));
    *(uint2*)(xs + row * 256 + (colb ^ ((row & 7) << 4))) = make_uint2(p0, p1);
  }

  // per-lane W base: (g, kt=0, kgrp=lg, c = wn*48 + lr, e=0)
  const unsigned short* bp = Wb + (size_t)g * (NKT_ * 6144) + lg * 1536 + (wn * 48 + lr) * 8;

  f32x4 acc[4][3];
#pragma unroll
  for (int mi = 0; mi < 4; ++mi)
#pragma unroll
    for (int nj = 0; nj < 3; ++nj) acc[mi][nj] = (f32x4)0.f;

  __syncthreads();                               // xs ready

  // ---- GEMM: M=128 x N=192 x K=384, fully unrolled, no barriers ----
#pragma unroll
  for (int kt = 0; kt < NKT_; ++kt) {
    const int kof = kt >> 2;                     // conv tap 0..2
    const int cb = (kt & 3) * 64 + lg * 16;      // byte col in xs row
    s16x8 b[3], a[4];
#pragma unroll
    for (int nj = 0; nj < 3; ++nj)
      b[nj] = *(const s16x8*)(bp + kt * 6144 + nj * 128);
#pragma unroll
    for (int mi = 0; mi < 4; ++mi) {
      const int row = wm * 64 + mi * 16 + lr + kof;
      a[mi] = *(const s16x8*)(xs + row * 256 + (cb ^ ((row & 7) << 4)));
    }
#pragma unroll
    for (int mi = 0; mi < 4; ++mi)
#pragma unroll
      for (int nj = 0; nj < 3; ++nj)
        acc[mi][nj] = __builtin_amdgcn_mfma_f32_16x16x32_bf16(a[mi], b[nj], acc[mi][nj], 0, 0, 0);
  }

  // ---- wave-parallel fo-pool scan: 4 passes of 32 rows; 4-step sub-chunks ----
  const float bz = bias[g * 64 + l];
  const float bf = bias[256 + g * 64 + l];
  const float bo = bias[512 + g * 64 + l];

#pragma unroll
  for (int p = 0; p < 4; ++p) {
    __syncthreads();                             // prev readers done (xs / pass p-1 gs)
    if (wm == (p >> 1)) {                        // 4 waves own this pass's 32 rows
#pragma unroll
      for (int mo = 0; mo < 2; ++mo) {
        const int mi = 2 * (p & 1) + mo;         // static index (unrolled)
#pragma unroll
        for (int nj = 0; nj < 3; ++nj)
#pragma unroll
          for (int r = 0; r < 4; ++r) {
            const int rl = mo * 16 + lg * 4 + r; // C frag: col=l&15, row=(l>>4)*4+r
            gs[rl * GP_ + wn * 48 + nj * 16 + lr] = acc[mi][nj][r];
          }
      }
    }
    __syncthreads();
    // wave w scans rows [4w, 4w+4) of this pass; 64 lanes = 64 h channels
    float P = 1.f, S = 0.f;
#pragma unroll
    for (int mt = 0; mt < 4; ++mt) {
      const int t = t0 + p * 32 + w * 4 + mt;
      if (t < T_) {
        const int rl = w * 4 + mt;
        const float zr = gs[rl * GP_ + l] + bz;
        const float fr = gs[rl * GP_ + 64 + l] + bf;
        const float orr = gs[rl * GP_ + 128 + l] + bo;
        const float zc = fminf(fmaxf(zr, -15.f), 15.f);
        const float e2 = __expf(2.f * zc);
        const float zt = (e2 - 1.f) * __builtin_amdgcn_rcpf(e2 + 1.f);
        const float ft = __builtin_amdgcn_rcpf(1.f + __expf(-fr));
        const float ot = __builtin_amdgcn_rcpf(1.f + __expf(-orr));
        const float A = ot * ft;
        const float Bv = ot * (1.f - ft) * zt;
        S = A * S + Bv;
        P = A * P;
      }
    }
    const int ci = p * 8 + w;                    // time-ordered sub-chunk id
    pbuf[ci * 128 + 2 * l] = P;
    pbuf[ci * 128 + 2 * l + 1] = S;
  }

  // ---- compose the block's 32 sub-chunks -> one affine (P,S) ----
  __syncthreads();
  if (w == 0) {
    float P = 1.f, S = 0.f;
#pragma unroll 8
    for (int ci = 0; ci < 32; ++ci) {
      const float pp = pbuf[ci * 128 + 2 * l];
      const float ss = pbuf[ci * 128 + 2 * l + 1];
      S = pp * S + ss;
      P = pp * P;
    }
    const size_t o = ((size_t)bb * NTB_ + tblk) * H_ + g * 64 + l;
    Pc[o] = P;
    Sc[o] = S;
  }
}

// ---------------------------------------------------------------------------
// Kernel 2: compose the 32 block-affine maps per (b,h) -> final h_T
// ---------------------------------------------------------------------------
__global__ __launch_bounds__(256) void combine_kernel(const float* __restrict__ Pc,
                                                      const float* __restrict__ Sc,
                                                      float* __restrict__ out) {
  const int idx = blockIdx.x * 256 + threadIdx.x;  // 8192 = B*H
  const int b = idx >> 8;
  const int h = idx & 255;
  float hv = 0.f;
#pragma unroll 8
  for (int c = 0; c < NTB_; ++c) {
    const float p = Pc[((size_t)b * NTB_ + c) * H_ + h];
    const float s = Sc[((size_t)b * NTB_ + c) * H_ + h];
    hv = p * hv + s;
  }
  out[idx] = hv;
}

// ---------------------------------------------------------------------------
extern "C" void kernel_launch(void* const* d_in, const int* in_sizes, int n_in,
                              void* d_out, int out_size, void* d_ws, size_t ws_size,
                              hipStream_t stream) {
  const float* x = (const float*)d_in[0];
  const float* W = (const float*)d_in[1];
  const float* bias = (const float*)d_in[2];
  float* out = (float*)d_out;

  char* ws = (char*)d_ws;
  unsigned short* Wb = (unsigned short*)ws;        // 576 KB
  float* Pc = (float*)(ws + (1 << 20));            // 1 MB (32*32*256 f32)
  float* Sc = (float*)(ws + 2 * (1 << 20));        // 1 MB

  packW_bf16<<<1152, 256, 0, stream>>>(W, Wb);
  conv_scan_mfma<<<dim3(1024, 4), 512, 0, stream>>>(x, Wb, bias, Pc, Sc);
  combine_kernel<<<32, 256, 0, stream>>>(Pc, Sc, out);
}

// Round 6
// 209.173 us; speedup vs baseline: 1.2057x; 1.2057x over previous
//
#include <hip/hip_runtime.h>
#include <math.h>

// Problem constants
#define B_    32
#define L_    4096
#define CIN_  128
#define H_    256
#define T_    4094          // L - K + 1
#define KTOT_ 384           // CIN * K

#define MT_   64            // timesteps per block (M tile)
#define NTB_  64            // t-blocks (64 * 64 = 4096)
#define NG_   192           // channels per block (z,f,o x 64 h)
#define NKT_  12            // K-steps of 32
#define GP_   196           // gate LDS pitch in f32

typedef float f32x4 __attribute__((ext_vector_type(4)));
typedef short s16x8 __attribute__((ext_vector_type(8)));

static __device__ __forceinline__ unsigned short f2bf(float f) {
  unsigned u = __builtin_bit_cast(unsigned, f);
  u = (u + 0x7FFFu + ((u >> 16) & 1u)) >> 16;
  return (unsigned short)u;
}

// ---------------------------------------------------------------------------
// Kernel 0: pack W (oc, i, k) fp32 -> bf16 [g][kt][kgrp][c192][e8].
// Reads coalesced (idx = source flat index); writes scattered (fire-and-forget).
// ---------------------------------------------------------------------------
__global__ __launch_bounds__(256) void packW_bf16(const float* __restrict__ W,
                                                  unsigned short* __restrict__ Wb) {
  const int idx = blockIdx.x * 256 + threadIdx.x;     // 294912 = 1152*256
  const int oc = idx / KTOT_;
  const int rem = idx - oc * KTOT_;
  const int i = rem / 3;
  const int k = rem - i * 3;
  const int kk = k * 128 + i;
  const int kt = kk >> 5;
  const int kgrp = (kk >> 3) & 3;
  const int e = kk & 7;
  const int gate = oc >> 8;
  const int g = (oc >> 6) & 3;
  const int hl = oc & 63;
  const int c = gate * 64 + hl;
  Wb[(size_t)g * 73728 + kt * 6144 + kgrp * 1536 + c * 8 + e] = f2bf(W[idx]);
}

// ---------------------------------------------------------------------------
// Kernel 1: fused bf16-MFMA conv + activations + fo-pool scan + block compose.
// grid 8192 = (tblk*32 + bb)*4 + g  (g in low bits -> the 4 blocks sharing an
// x-slice are dispatch-adjacent -> concurrent -> L3 serves 3 of 4 reads).
// block 512 (8 waves = 2M x 4N, per-wave 32x48 -> acc[2][3] = 24 AGPR).
// Barrier-free K-loop (A in LDS read-only, B global->VGPR from L1/L2).
// ---------------------------------------------------------------------------
__global__ __launch_bounds__(512, 6) void conv_scan_mfma(
    const float* __restrict__ x, const unsigned short* __restrict__ Wb,
    const float* __restrict__ bias, float* __restrict__ Pc,
    float* __restrict__ Sc) {
  // xs: 66 rows x 128 bf16 (256B pitch, XOR-swizzled) = 16896 B
  // gs (scan, overlays xs): 32 x GP_ f32               = 25088 B
  // pbuf (after gs): 16 chunks x 64 x 2 f32            =  8192 B
  __shared__ __align__(16) char smem[25088 + 8192];
  char* xs = smem;
  float* gs = (float*)smem;
  float* pbuf = (float*)(smem + 25088);

  const int tid = threadIdx.x;
  const int w = tid >> 6;              // wave 0..7
  const int wm = w >> 2;               // M half: rows [32*wm, 32*wm+32)
  const int wn = w & 3;                // N quarter: cols [48*wn, 48*wn+48)
  const int l = tid & 63;
  const int lr = l & 15;
  const int lg = l >> 4;
  const int bid = blockIdx.x;
  const int g = bid & 3;               // h-group (low bits: x-slice sharers adjacent)
  const int r2 = bid >> 2;
  const int bb = r2 & 31;
  const int tblk = r2 >> 5;            // 0..63
  const int t0 = tblk * MT_;

  // ---- stage x slice (66 rows) fp32 -> bf16 into swizzled xs ----
  for (int v = tid; v < 66 * 32; v += 512) {
    const int row = v >> 5;
    const int colb = (v & 31) * 8;               // byte offset of 4 bf16
    int r = t0 + row;
    if (r > L_ - 1) r = L_ - 1;                  // clamp; feeds only t>=T_, skipped
    const float4 xv = *(const float4*)&x[((size_t)bb * L_ + r) * CIN_ + (v & 31) * 4];
    unsigned p0, p1;
    asm("v_cvt_pk_bf16_f32 %0, %1, %2" : "=v"(p0) : "v"(xv.x), "v"(xv.y));
    asm("v_cvt_pk_bf16_f32 %0, %1, %2" : "=v"(p1) : "v"(xv.z), "v"(xv.w));
    *(uint2*)(xs + row * 256 + (colb ^ ((row & 7) << 4))) = make_uint2(p0, p1);
  }

  // per-lane W base: (g, kt=0, kgrp=lg, c = wn*48 + lr, e=0)
  const unsigned short* bp = Wb + (size_t)g * 73728 + lg * 1536 + (wn * 48 + lr) * 8;

  f32x4 acc[2][3];
#pragma unroll
  for (int mi = 0; mi < 2; ++mi)
#pragma unroll
    for (int nj = 0; nj < 3; ++nj) acc[mi][nj] = (f32x4)0.f;

  __syncthreads();                               // xs ready

  // ---- GEMM: M=64 x N=192 x K=384, fully unrolled, no barriers ----
#pragma unroll
  for (int kt = 0; kt < NKT_; ++kt) {
    const int kof = kt >> 2;                     // conv tap 0..2
    const int cb = (kt & 3) * 64 + lg * 16;      // byte col in xs row
    s16x8 b[3], a[2];
#pragma unroll
    for (int nj = 0; nj < 3; ++nj)
      b[nj] = *(const s16x8*)(bp + kt * 6144 + nj * 128);
#pragma unroll
    for (int mi = 0; mi < 2; ++mi) {
      const int row = wm * 32 + mi * 16 + lr + kof;
      a[mi] = *(const s16x8*)(xs + row * 256 + (cb ^ ((row & 7) << 4)));
    }
#pragma unroll
    for (int mi = 0; mi < 2; ++mi)
#pragma unroll
      for (int nj = 0; nj < 3; ++nj)
        acc[mi][nj] = __builtin_amdgcn_mfma_f32_16x16x32_bf16(a[mi], b[nj], acc[mi][nj], 0, 0, 0);
  }

  // ---- wave-parallel fo-pool scan: 2 passes of 32 rows; 4-step sub-chunks ----
  const float bz = bias[g * 64 + l];
  const float bf = bias[256 + g * 64 + l];
  const float bo = bias[512 + g * 64 + l];

#pragma unroll
  for (int p = 0; p < 2; ++p) {
    __syncthreads();                             // prev readers done (xs / pass 0 gs)
    if (wm == p) {                               // 4 waves own this pass's 32 rows
#pragma unroll
      for (int mi = 0; mi < 2; ++mi)
#pragma unroll
        for (int nj = 0; nj < 3; ++nj)
#pragma unroll
          for (int r = 0; r < 4; ++r) {
            const int rl = mi * 16 + lg * 4 + r; // C frag: col=l&15, row=(l>>4)*4+r
            gs[rl * GP_ + wn * 48 + nj * 16 + lr] = acc[mi][nj][r];
          }
    }
    __syncthreads();
    // wave w scans rows [4w, 4w+4) of this pass; 64 lanes = 64 h channels
    float P = 1.f, S = 0.f;
#pragma unroll
    for (int mt = 0; mt < 4; ++mt) {
      const int t = t0 + p * 32 + w * 4 + mt;
      if (t < T_) {
        const int rl = w * 4 + mt;
        const float zr = gs[rl * GP_ + l] + bz;
        const float fr = gs[rl * GP_ + 64 + l] + bf;
        const float orr = gs[rl * GP_ + 128 + l] + bo;
        const float zc = fminf(fmaxf(zr, -15.f), 15.f);
        const float e2 = __expf(2.f * zc);
        const float zt = (e2 - 1.f) * __builtin_amdgcn_rcpf(e2 + 1.f);
        const float ft = __builtin_amdgcn_rcpf(1.f + __expf(-fr));
        const float ot = __builtin_amdgcn_rcpf(1.f + __expf(-orr));
        const float A = ot * ft;
        const float Bv = ot * (1.f - ft) * zt;
        S = A * S + Bv;
        P = A * P;
      }
    }
    const int ci = p * 8 + w;                    // time-ordered sub-chunk id
    pbuf[ci * 128 + 2 * l] = P;
    pbuf[ci * 128 + 2 * l + 1] = S;
  }

  // ---- compose the block's 16 sub-chunks -> one affine (P,S) ----
  __syncthreads();
  if (w == 0) {
    float P = 1.f, S = 0.f;
#pragma unroll 4
    for (int ci = 0; ci < 16; ++ci) {
      const float pp = pbuf[ci * 128 + 2 * l];
      const float ss = pbuf[ci * 128 + 2 * l + 1];
      S = pp * S + ss;
      P = pp * P;
    }
    const size_t o = ((size_t)bb * NTB_ + tblk) * H_ + g * 64 + l;
    Pc[o] = P;
    Sc[o] = S;
  }
}

// ---------------------------------------------------------------------------
// Kernel 2: compose the 64 block-affine maps per (b,h) -> final h_T
// ---------------------------------------------------------------------------
__global__ __launch_bounds__(256) void combine_kernel(const float* __restrict__ Pc,
                                                      const float* __restrict__ Sc,
                                                      float* __restrict__ out) {
  const int idx = blockIdx.x * 256 + threadIdx.x;  // 8192 = B*H
  const int b = idx >> 8;
  const int h = idx & 255;
  float hv = 0.f;
#pragma unroll 8
  for (int c = 0; c < NTB_; ++c) {
    const float p = Pc[((size_t)b * NTB_ + c) * H_ + h];
    const float s = Sc[((size_t)b * NTB_ + c) * H_ + h];
    hv = p * hv + s;
  }
  out[idx] = hv;
}

// ---------------------------------------------------------------------------
extern "C" void kernel_launch(void* const* d_in, const int* in_sizes, int n_in,
                              void* d_out, int out_size, void* d_ws, size_t ws_size,
                              hipStream_t stream) {
  const float* x = (const float*)d_in[0];
  const float* W = (const float*)d_in[1];
  const float* bias = (const float*)d_in[2];
  float* out = (float*)d_out;

  char* ws = (char*)d_ws;
  unsigned short* Wb = (unsigned short*)ws;        // 576 KB
  float* Pc = (float*)(ws + (1 << 20));            // 2 MB (32*64*256 f32)
  float* Sc = (float*)(ws + 3 * (1 << 20));        // 2 MB

  packW_bf16<<<1152, 256, 0, stream>>>(W, Wb);
  conv_scan_mfma<<<8192, 512, 0, stream>>>(x, Wb, bias, Pc, Sc);
  combine_kernel<<<32, 256, 0, stream>>>(Pc, Sc, out);
}

// Round 7
// 193.901 us; speedup vs baseline: 1.3006x; 1.0788x over previous
//
#include <hip/hip_runtime.h>
#include <math.h>

// Problem constants
#define B_    32
#define L_    4096
#define CIN_  128
#define H_    256
#define T_    4094          // L - K + 1
#define KTOT_ 384           // CIN * K

#define MT_   128           // timesteps per block (M tile)
#define NTB_  32            // t-blocks (32 * 128 = 4096)
#define NG_   192           // channels per block (z,f,o x 64 h)
#define NKT_  12            // K-steps of 32

typedef float f32x4 __attribute__((ext_vector_type(4)));
typedef short s16x8 __attribute__((ext_vector_type(8)));

static __device__ __forceinline__ unsigned short f2bf(float f) {
  unsigned u = __builtin_bit_cast(unsigned, f);
  u = (u + 0x7FFFu + ((u >> 16) & 1u)) >> 16;
  return (unsigned short)u;
}

// ---------------------------------------------------------------------------
// Kernel 0: pack W (oc,i,k) fp32 -> bf16 [g][kt][kgrp][c192][e8], where the
// 192 block-columns are GATE-INTERLEAVED: col c -> q=c>>4, lr=c&15;
// gate = q%3, h_lo = (q/3)*16 + lr.  Consequence: wave wn's fragment nj holds
// gate nj for h-channels wn*16+lr -> the fo-pool scan runs entirely in
// registers (no LDS gate exchange).  One thread emits 8 contiguous bf16.
// ---------------------------------------------------------------------------
__global__ __launch_bounds__(256) void packW_bf16(const float* __restrict__ W,
                                                  unsigned short* __restrict__ Wb) {
  const int tidg = blockIdx.x * 256 + threadIdx.x;    // 36864 = 144*256
  const int c = tidg % NG_;
  int t = tidg / NG_;
  const int kgrp = t & 3;  t >>= 2;
  const int kt = t % NKT_;
  const int g = t / NKT_;
  const int q = c >> 4, lr = c & 15;
  const int gate = q % 3, hgrp = q / 3;
  const int hl = hgrp * 16 + lr;
  const int oc = gate * 256 + g * 64 + hl;
  s16x8 outv;
#pragma unroll
  for (int e = 0; e < 8; ++e) {
    const int kk = kt * 32 + kgrp * 8 + e;
    const int i = kk & 127, k = kk >> 7;
    outv[e] = (short)f2bf(W[(size_t)oc * KTOT_ + i * 3 + k]);
  }
  *(s16x8*)(Wb + (size_t)tidg * 8) = outv;            // coalesced 16B store
}

// ---------------------------------------------------------------------------
// Kernel 1: fused bf16-MFMA conv + in-register fo-pool scan + block compose.
// grid 4096 = (tblk*32 + bb)*4 + g  (g-adjacent -> x-slice sharers concurrent)
// block 512 (8 waves = 2M x 4N; per-wave 64x48; acc[4][3] = 48 AGPR).
// Barrier-free K-loop, B global->VGPR with explicit 1-deep prefetch.
// ---------------------------------------------------------------------------
__global__ __launch_bounds__(512, 4) void conv_scan_mfma(
    const float* __restrict__ x, const unsigned short* __restrict__ Wb,
    const float* __restrict__ bias, float* __restrict__ Pc,
    float* __restrict__ Sc) {
  // xs: 130 rows x 128 bf16 (256B pitch, XOR-swizzled) = 33280 B
  // wmbuf: 2 x 64 float2 (cross-wm affine exchange)    =  1024 B
  __shared__ __align__(16) char smem[33280 + 1024];
  char* xs = smem;
  float2* wmbuf = (float2*)(smem + 33280);

  const int tid = threadIdx.x;
  const int w = tid >> 6;              // wave 0..7
  const int wm = w >> 2;               // M half: rows [64*wm, 64*wm+64)
  const int wn = w & 3;                // N quarter: cols [48*wn, 48*wn+48)
  const int l = tid & 63;
  const int lr = l & 15;
  const int lg = l >> 4;
  const int bid = blockIdx.x;
  const int g = bid & 3;               // h-group (low bits -> L3 reuse of x)
  const int r2 = bid >> 2;
  const int bb = r2 & 31;
  const int tblk = r2 >> 5;            // 0..31
  const int t0 = tblk * MT_;

  // per-lane W base: (g, kt, kgrp=lg, c = wn*48 + nj*16 + lr)
  const unsigned short* bp = Wb + (size_t)g * 73728 + lg * 1536 + (wn * 48 + lr) * 8;

  // issue kt=0 B fragments early (overlap with x staging)
  s16x8 bcur[3];
#pragma unroll
  for (int nj = 0; nj < 3; ++nj)
    bcur[nj] = *(const s16x8*)(bp + nj * 128);

  // ---- stage x slice (130 rows) fp32 -> bf16 into swizzled xs ----
  for (int v = tid; v < 130 * 32; v += 512) {
    const int row = v >> 5;
    const int colb = (v & 31) * 8;               // byte offset of 4 bf16
    int r = t0 + row;
    if (r > L_ - 1) r = L_ - 1;                  // clamp; feeds only t>=T_ (identity)
    const float4 xv = *(const float4*)&x[((size_t)bb * L_ + r) * CIN_ + (v & 31) * 4];
    unsigned p0, p1;
    asm("v_cvt_pk_bf16_f32 %0, %1, %2" : "=v"(p0) : "v"(xv.x), "v"(xv.y));
    asm("v_cvt_pk_bf16_f32 %0, %1, %2" : "=v"(p1) : "v"(xv.z), "v"(xv.w));
    *(uint2*)(xs + row * 256 + (colb ^ ((row & 7) << 4))) = make_uint2(p0, p1);
  }

  f32x4 acc[4][3];
#pragma unroll
  for (int mi = 0; mi < 4; ++mi)
#pragma unroll
    for (int nj = 0; nj < 3; ++nj) acc[mi][nj] = (f32x4)0.f;

  __syncthreads();                               // xs ready

  // ---- GEMM: M=128 x N=192 x K=384; no barriers; 1-deep B prefetch ----
#pragma unroll
  for (int kt = 0; kt < NKT_; ++kt) {
    s16x8 bnxt[3];
    if (kt < NKT_ - 1) {                         // static under full unroll
#pragma unroll
      for (int nj = 0; nj < 3; ++nj)
        bnxt[nj] = *(const s16x8*)(bp + (kt + 1) * 6144 + nj * 128);
    }
    const int kof = kt >> 2;                     // conv tap 0..2
    const int cb = (kt & 3) * 64 + lg * 16;      // byte col in xs row
    s16x8 a[4];
#pragma unroll
    for (int mi = 0; mi < 4; ++mi) {
      const int row = wm * 64 + mi * 16 + lr + kof;
      a[mi] = *(const s16x8*)(xs + row * 256 + (cb ^ ((row & 7) << 4)));
    }
#pragma unroll
    for (int mi = 0; mi < 4; ++mi)
#pragma unroll
      for (int nj = 0; nj < 3; ++nj)
        acc[mi][nj] = __builtin_amdgcn_mfma_f32_16x16x32_bf16(a[mi], bcur[nj], acc[mi][nj], 0, 0, 0);
    if (kt < NKT_ - 1) {
#pragma unroll
      for (int nj = 0; nj < 3; ++nj) bcur[nj] = bnxt[nj];
    }
  }

  // ---- in-register fo-pool scan ----
  // Lane holds gates z,f,o (nj=0,1,2) for h_lo = wn*16+lr at rows
  // wm*64 + mi*16 + lg*4 + r.  Compose: 4-step run (serial r) ->
  // cross-lg shfl compose -> serial mi -> cross-wm via 1KB LDS.
  const int hl = wn * 16 + lr;
  const float bz = bias[g * 64 + hl];
  const float bf_ = bias[256 + g * 64 + hl];
  const float bo_ = bias[512 + g * 64 + hl];

  float Pw = 1.f, Sw = 0.f;
#pragma unroll
  for (int mi = 0; mi < 4; ++mi) {
    float Pr = 1.f, Sr = 0.f;
#pragma unroll
    for (int r = 0; r < 4; ++r) {
      const int t = t0 + wm * 64 + mi * 16 + lg * 4 + r;
      const float zr = acc[mi][0][r] + bz;
      const float fr = acc[mi][1][r] + bf_;
      const float orr = acc[mi][2][r] + bo_;
      const float zc = fminf(fmaxf(zr, -15.f), 15.f);
      const float e2 = __expf(2.f * zc);
      const float zt = (e2 - 1.f) * __builtin_amdgcn_rcpf(e2 + 1.f);
      const float ft = __builtin_amdgcn_rcpf(1.f + __expf(-fr));
      const float ot = __builtin_amdgcn_rcpf(1.f + __expf(-orr));
      float A = ot * ft;
      float Bv = ot * (1.f - ft) * zt;
      const bool valid = (t < T_);
      A = valid ? A : 1.f;                       // identity for padded steps
      Bv = valid ? Bv : 0.f;
      Sr = A * Sr + Bv;
      Pr = A * Pr;
    }
    // compose across lg (t-stride 4): stage 1 pairs lg {0,1},{2,3}
    float Pp = __shfl_xor(Pr, 16), Sp = __shfl_xor(Sr, 16);
    if (lg & 1) { Sr = Pr * Sp + Sr; Pr = Pr * Pp; }
    else        { Sr = Pp * Sr + Sp; Pr = Pp * Pr; }
    Pp = __shfl_xor(Pr, 32); Sp = __shfl_xor(Sr, 32);
    if (lg & 2) { Sr = Pr * Sp + Sr; Pr = Pr * Pp; }
    else        { Sr = Pp * Sr + Sp; Pr = Pp * Pr; }
    // (Pr,Sr) = this wave's 16-step group mi (same in all lg lanes)
    Sw = Pr * Sw + Sr;
    Pw = Pr * Pw;
  }

  if (lg == 0) wmbuf[wm * 64 + hl] = make_float2(Pw, Sw);
  __syncthreads();
  if (tid < 64) {
    const float2 e0 = wmbuf[tid];                // rows 0..63   (earlier)
    const float2 e1 = wmbuf[64 + tid];           // rows 64..127 (later)
    const float P = e1.x * e0.x;
    const float S = e1.x * e0.y + e1.y;
    const size_t o = ((size_t)bb * NTB_ + tblk) * H_ + g * 64 + tid;
    Pc[o] = P;
    Sc[o] = S;
  }
}

// ---------------------------------------------------------------------------
// Kernel 2: compose the 32 block-affine maps per (b,h) -> final h_T
// ---------------------------------------------------------------------------
__global__ __launch_bounds__(128) void combine_kernel(const float* __restrict__ Pc,
                                                      const float* __restrict__ Sc,
                                                      float* __restrict__ out) {
  const int idx = blockIdx.x * 128 + threadIdx.x;  // 8192 = B*H
  const int b = idx >> 8;
  const int h = idx & 255;
  float hv = 0.f;
#pragma unroll 8
  for (int c = 0; c < NTB_; ++c) {
    const float p = Pc[((size_t)b * NTB_ + c) * H_ + h];
    const float s = Sc[((size_t)b * NTB_ + c) * H_ + h];
    hv = p * hv + s;
  }
  out[idx] = hv;
}

// ---------------------------------------------------------------------------
extern "C" void kernel_launch(void* const* d_in, const int* in_sizes, int n_in,
                              void* d_out, int out_size, void* d_ws, size_t ws_size,
                              hipStream_t stream) {
  const float* x = (const float*)d_in[0];
  const float* W = (const float*)d_in[1];
  const float* bias = (const float*)d_in[2];
  float* out = (float*)d_out;

  char* ws = (char*)d_ws;
  unsigned short* Wb = (unsigned short*)ws;        // 576 KB
  float* Pc = (float*)(ws + (1 << 20));            // 1 MB (32*32*256 f32)
  float* Sc = (float*)(ws + 2 * (1 << 20));        // 1 MB

  packW_bf16<<<144, 256, 0, stream>>>(W, Wb);
  conv_scan_mfma<<<4096, 512, 0, stream>>>(x, Wb, bias, Pc, Sc);
  combine_kernel<<<64, 128, 0, stream>>>(Pc, Sc, out);
}

// Round 9
// 182.860 us; speedup vs baseline: 1.3792x; 1.0604x over previous
//
#include <hip/hip_runtime.h>
#include <math.h>

// Problem constants
#define B_    32
#define L_    4096
#define CIN_  128
#define H_    256
#define T_    4094          // L - K + 1
#define KTOT_ 384           // CIN * K

#define MT_   64            // timesteps per block (M tile)
#define NTB_  64            // t-blocks (64 * 64 = 4096)
#define NKT_  12            // K-steps of 32

typedef float f32x4 __attribute__((ext_vector_type(4)));
typedef short s16x8 __attribute__((ext_vector_type(8)));

static __device__ __forceinline__ unsigned short f2bf(float f) {
  unsigned u = __builtin_bit_cast(unsigned, f);
  u = (u + 0x7FFFu + ((u >> 16) & 1u)) >> 16;
  return (unsigned short)u;
}

// ---------------------------------------------------------------------------
// Kernel 0: pack W (oc,i,k) fp32 -> bf16 [kt 12][kgrp 4][c 768][e 8], with the
// 768 columns GATE-INTERLEAVED: c -> q=c>>4, lr=c&15; gate=q%3, hgrp=q/3;
// oc = gate*256 + hgrp*16 + lr.  Consequence: wave wn (0..15), fragment nj
// holds gate nj for h = wn*16+lr -> fo-pool scan runs entirely in registers.
// One thread emits 8 contiguous bf16 (coalesced 16B store).
// ---------------------------------------------------------------------------
__global__ __launch_bounds__(256) void packW_bf16(const float* __restrict__ W,
                                                  unsigned short* __restrict__ Wb) {
  const int idx = blockIdx.x * 256 + threadIdx.x;     // 36864 = 144*256
  const int c = idx % 768;
  const int t = idx / 768;
  const int kgrp = t & 3;
  const int kt = t >> 2;                              // 0..11
  const int q = c >> 4, lr = c & 15;
  const int gate = q % 3, hgrp = q / 3;
  const int oc = gate * 256 + hgrp * 16 + lr;
  s16x8 outv;
#pragma unroll
  for (int e = 0; e < 8; ++e) {
    const int kk = kt * 32 + kgrp * 8 + e;
    const int i = kk & 127, k = kk >> 7;
    outv[e] = (short)f2bf(W[(size_t)oc * KTOT_ + i * 3 + k]);
  }
  *(s16x8*)(Wb + (size_t)idx * 8) = outv;
}

// ---------------------------------------------------------------------------
// Kernel 1: fused bf16-MFMA conv + in-register fo-pool scan.
// grid 2048 = tblk*32 + bb; block 1024 (16 waves = 1M x 16N).
// Per block: M=64 timesteps x N=768 channels x K=384 -> x staged ONCE.
// Wave wn: cols [48*wn, 48*wn+48) = gates z,f,o for h in [16*wn, 16*wn+16).
// ONE barrier total; K-loop barrier-free (A in LDS read-only, B global->VGPR).
// ---------------------------------------------------------------------------
__global__ __launch_bounds__(1024, 4) void conv_scan_mfma(
    const float* __restrict__ x, const unsigned short* __restrict__ Wb,
    const float* __restrict__ bias, float* __restrict__ Pc,
    float* __restrict__ Sc) {
  // xs: 66 rows x 128 bf16 (256B pitch, XOR-swizzled) = 16896 B
  __shared__ __align__(16) char xs[66 * 256];

  const int tid = threadIdx.x;
  const int wn = tid >> 6;             // wave 0..15 -> h group [16*wn, 16*wn+16)
  const int l = tid & 63;
  const int lr = l & 15;
  const int lg = l >> 4;
  const int bid = blockIdx.x;
  const int bb = bid & 31;
  const int tblk = bid >> 5;           // 0..63
  const int t0 = tblk * MT_;

  // per-lane W base: (kt=0, kgrp=lg, c = wn*48 + nj*16 + lr, e=0)
  const unsigned short* bp = Wb + lg * 6144 + (wn * 48 + lr) * 8;

  // issue kt=0 B fragments early (overlap with x staging)
  s16x8 bcur[3];
#pragma unroll
  for (int nj = 0; nj < 3; ++nj)
    bcur[nj] = *(const s16x8*)(bp + nj * 128);

  // ---- stage x slice (66 rows) fp32 -> bf16 into swizzled xs ----
  for (int v = tid; v < 66 * 32; v += 1024) {
    const int row = v >> 5;
    const int colb = (v & 31) * 8;               // byte offset of 4 bf16
    int r = t0 + row;
    if (r > L_ - 1) r = L_ - 1;                  // clamp; feeds only t>=T_ (identity)
    const float4 xv = *(const float4*)&x[((size_t)bb * L_ + r) * CIN_ + (v & 31) * 4];
    unsigned p0, p1;
    asm("v_cvt_pk_bf16_f32 %0, %1, %2" : "=v"(p0) : "v"(xv.x), "v"(xv.y));
    asm("v_cvt_pk_bf16_f32 %0, %1, %2" : "=v"(p1) : "v"(xv.z), "v"(xv.w));
    *(uint2*)(xs + row * 256 + (colb ^ ((row & 7) << 4))) = make_uint2(p0, p1);
  }

  f32x4 acc[4][3];
#pragma unroll
  for (int mi = 0; mi < 4; ++mi)
#pragma unroll
    for (int nj = 0; nj < 3; ++nj) acc[mi][nj] = (f32x4)0.f;

  __syncthreads();                               // xs ready — the ONLY barrier

  // ---- GEMM: M=64 x N=768 x K=384; no barriers; 1-deep B prefetch ----
#pragma unroll
  for (int kt = 0; kt < NKT_; ++kt) {
    s16x8 bnxt[3];
    if (kt < NKT_ - 1) {                         // static under full unroll
#pragma unroll
      for (int nj = 0; nj < 3; ++nj)
        bnxt[nj] = *(const s16x8*)(bp + (kt + 1) * 24576 + nj * 128);
    }
    const int kof = kt >> 2;                     // conv tap 0..2
    const int cb = (kt & 3) * 64 + lg * 16;      // byte col in xs row
    s16x8 a[4];
#pragma unroll
    for (int mi = 0; mi < 4; ++mi) {
      const int row = mi * 16 + lr + kof;
      a[mi] = *(const s16x8*)(xs + row * 256 + (cb ^ ((row & 7) << 4)));
    }
#pragma unroll
    for (int mi = 0; mi < 4; ++mi)
#pragma unroll
      for (int nj = 0; nj < 3; ++nj)
        acc[mi][nj] = __builtin_amdgcn_mfma_f32_16x16x32_bf16(a[mi], bcur[nj], acc[mi][nj], 0, 0, 0);
    if (kt < NKT_ - 1) {
#pragma unroll
      for (int nj = 0; nj < 3; ++nj) bcur[nj] = bnxt[nj];
    }
  }

  // ---- in-register fo-pool scan ----
  // Lane holds z,f,o (nj=0,1,2) for h = wn*16+lr at rows mi*16 + lg*4 + r.
  // Compose: serial 4-step run -> cross-lg shfl compose -> serial mi.
  const int hl = wn * 16 + lr;
  const float bz = bias[hl];
  const float bf_ = bias[256 + hl];
  const float bo_ = bias[512 + hl];

  float Pw = 1.f, Sw = 0.f;
#pragma unroll
  for (int mi = 0; mi < 4; ++mi) {
    float Pr = 1.f, Sr = 0.f;
#pragma unroll
    for (int r = 0; r < 4; ++r) {
      const int t = t0 + mi * 16 + lg * 4 + r;
      const float zr = acc[mi][0][r] + bz;
      const float fr = acc[mi][1][r] + bf_;
      const float orr = acc[mi][2][r] + bo_;
      const float zc = fminf(fmaxf(zr, -15.f), 15.f);
      const float e2 = __expf(2.f * zc);
      const float zt = (e2 - 1.f) * __builtin_amdgcn_rcpf(e2 + 1.f);
      const float ft = __builtin_amdgcn_rcpf(1.f + __expf(-fr));
      const float ot = __builtin_amdgcn_rcpf(1.f + __expf(-orr));
      float A = ot * ft;
      float Bv = ot * (1.f - ft) * zt;
      const bool valid = (t < T_);
      A = valid ? A : 1.f;                       // identity for padded steps
      Bv = valid ? Bv : 0.f;
      Sr = A * Sr + Bv;
      Pr = A * Pr;
    }
    // compose across lg (t-stride 4): later-composed-with-earlier
    float Pp = __shfl_xor(Pr, 16), Sp = __shfl_xor(Sr, 16);
    if (lg & 1) { Sr = Pr * Sp + Sr; Pr = Pr * Pp; }
    else        { Sr = Pp * Sr + Sp; Pr = Pp * Pr; }
    Pp = __shfl_xor(Pr, 32); Sp = __shfl_xor(Sr, 32);
    if (lg & 2) { Sr = Pr * Sp + Sr; Pr = Pr * Pp; }
    else        { Sr = Pp * Sr + Sp; Pr = Pp * Pr; }
    // (Pr,Sr) = 16-step group mi (identical across lg); mi ascending in time
    Sw = Pr * Sw + Sr;
    Pw = Pr * Pw;
  }

  if (lg == 0) {                                 // 16 lanes/wave write 16 h each
    const size_t o = ((size_t)bb * NTB_ + tblk) * H_ + hl;
    Pc[o] = Pw;
    Sc[o] = Sw;
  }
}

// ---------------------------------------------------------------------------
// Kernel 2: compose the 64 block-affine maps per (b,h) -> final h_T
// ---------------------------------------------------------------------------
__global__ __launch_bounds__(128) void combine_kernel(const float* __restrict__ Pc,
                                                      const float* __restrict__ Sc,
                                                      float* __restrict__ out) {
  const int idx = blockIdx.x * 128 + threadIdx.x;  // 8192 = B*H
  const int b = idx >> 8;
  const int h = idx & 255;
  float hv = 0.f;
#pragma unroll 8
  for (int c = 0; c < NTB_; ++c) {
    const float p = Pc[((size_t)b * NTB_ + c) * H_ + h];
    const float s = Sc[((size_t)b * NTB_ + c) * H_ + h];
    hv = p * hv + s;
  }
  out[idx] = hv;
}

// ---------------------------------------------------------------------------
extern "C" void kernel_launch(void* const* d_in, const int* in_sizes, int n_in,
                              void* d_out, int out_size, void* d_ws, size_t ws_size,
                              hipStream_t stream) {
  const float* x = (const float*)d_in[0];
  const float* W = (const float*)d_in[1];
  const float* bias = (const float*)d_in[2];
  float* out = (float*)d_out;

  char* ws = (char*)d_ws;
  unsigned short* Wb = (unsigned short*)ws;        // 576 KB
  float* Pc = (float*)(ws + (1 << 20));            // 2 MB (32*64*256 f32)
  float* Sc = (float*)(ws + 3 * (1 << 20));        // 2 MB

  packW_bf16<<<144, 256, 0, stream>>>(W, Wb);
  conv_scan_mfma<<<2048, 1024, 0, stream>>>(x, Wb, bias, Pc, Sc);
  combine_kernel<<<64, 128, 0, stream>>>(Pc, Sc, out);
}